// Round 5
// baseline (1258.747 us; speedup 1.0000x reference)
//
#include <hip/hip_runtime.h>
#include <hip/hip_bf16.h>
#include <math.h>

// Problem constants
#define NROWS 100000
#define DDIM  512
#define KCL   32
#define H1DIM 512
#define H2DIM 256
#define LN2PI_2 0.9189385332046727f
#define NCHUNK 196   // ceil(100000/512)

typedef __attribute__((ext_vector_type(8))) short short8;
typedef __attribute__((ext_vector_type(4))) short shortx4;
typedef __attribute__((ext_vector_type(4))) float floatx4;

// async global->LDS, 16B per lane, wave-uniform LDS base + lane*16
#define GLOAD_LDS16(gp, lp) __builtin_amdgcn_global_load_lds( \
    (const __attribute__((address_space(1))) void*)(gp), \
    (__attribute__((address_space(3))) void*)(lp), 16, 0, 0)

__device__ __forceinline__ float softplus_f(float v) {
    return v > 20.f ? v : log1pf(expf(v));
}

__device__ __forceinline__ unsigned short f2bf_rne(float f) {
    unsigned int u = __float_as_uint(f);
    return (unsigned short)((u + 0x7fffu + ((u >> 16) & 1u)) >> 16);
}

// ---------------------------------------------------------------------------
// x (fp32) -> bf16, 8 elements/thread.
// ---------------------------------------------------------------------------
__global__ __launch_bounds__(256) void cvt_x_bf16(
    const float* __restrict__ x, short* __restrict__ xb)
{
    size_t i = ((size_t)blockIdx.x * 256 + threadIdx.x) * 8;
    float4 f0 = *(const float4*)&x[i];
    float4 f1 = *(const float4*)&x[i + 4];
    short8 o;
    o[0] = (short)f2bf_rne(f0.x); o[1] = (short)f2bf_rne(f0.y);
    o[2] = (short)f2bf_rne(f0.z); o[3] = (short)f2bf_rne(f0.w);
    o[4] = (short)f2bf_rne(f1.x); o[5] = (short)f2bf_rne(f1.y);
    o[6] = (short)f2bf_rne(f1.z); o[7] = (short)f2bf_rne(f1.w);
    *(short8*)&xb[i] = o;
}

// ---------------------------------------------------------------------------
// W[k][n] fp32 -> transposed bf16 BT[n][k].
// ---------------------------------------------------------------------------
__global__ __launch_bounds__(256) void cvt_weightT(
    const float* __restrict__ W, int Kd, int Nc, short* __restrict__ BT)
{
    int idx = blockIdx.x * 256 + threadIdx.x;
    if (idx >= Kd * Nc) return;
    int n = idx % Nc, k = idx / Nc;
    BT[(size_t)n * Kd + k] = (short)f2bf_rne(W[idx]);
}

// ---------------------------------------------------------------------------
// C = softplus(A @ B^T + bias), m97-style: BK=32, unpadded [128][32] LDS
// tiles staged with global_load_lds width=16 (no VGPR round-trip).
// 256 thr = 4 waves, each 64x64 via 4x4 frags of mfma_f32_16x16x32_bf16.
// ---------------------------------------------------------------------------
__global__ __launch_bounds__(256) void gemm_bf16_softplus(
    const short* __restrict__ A, const short* __restrict__ BT,
    const float* __restrict__ bias, void* __restrict__ Cptr,
    int M, int Nc, int Kd, int out_bf16)
{
    __shared__ short As[128 * 32];   // 8 KB, unpadded (global_load_lds layout)
    __shared__ short Bs[128 * 32];   // 8 KB

    const int tid = threadIdx.x;
    const int lid = tid & 63;
    const int w = tid >> 6;
    const int lm = lid & 15;
    const int lq = lid >> 4;
    const int wrow = (w & 1) * 64;
    const int wcol = (w >> 1) * 64;

    const int row0 = blockIdx.y * 128;
    const int col0 = blockIdx.x * 128;

    // per-lane within-chunk coords for staging: 16 rows x 32 k per 1KB chunk
    const int sr = lid >> 2;         // 0..15 row within chunk
    const int sc = (lid & 3) << 3;   // 0,8,16,24 (shorts)

    floatx4 acc[4][4];
    #pragma unroll
    for (int i = 0; i < 4; i++)
        #pragma unroll
        for (int j = 0; j < 4; j++)
            acc[i][j] = (floatx4){0.f, 0.f, 0.f, 0.f};

    const int nk = Kd >> 5;
    for (int kt = 0; kt < nk; kt++) {
        const int k0 = kt << 5;
        __syncthreads();
        // ---- async stage: wave w loads chunks 2w,2w+1 of A and of B ----
        #pragma unroll
        for (int h = 0; h < 2; h++) {
            int rb = w * 32 + h * 16;            // chunk base row (wave-uniform)
            int gr = row0 + rb + sr;
            if (gr > M - 1) gr = M - 1;          // clamp (masked at store)
            GLOAD_LDS16(&A[(size_t)gr * Kd + k0 + sc], &As[rb * 32]);
            GLOAD_LDS16(&BT[(size_t)(col0 + rb + sr) * Kd + k0 + sc], &Bs[rb * 32]);
        }
        __syncthreads();

        short8 a[4], b[4];
        #pragma unroll
        for (int i = 0; i < 4; i++)
            a[i] = *(const short8*)&As[(wrow + i * 16 + lm) * 32 + lq * 8];
        #pragma unroll
        for (int j = 0; j < 4; j++)
            b[j] = *(const short8*)&Bs[(wcol + j * 16 + lm) * 32 + lq * 8];
        #pragma unroll
        for (int i = 0; i < 4; i++)
            #pragma unroll
            for (int j = 0; j < 4; j++)
                acc[i][j] = __builtin_amdgcn_mfma_f32_16x16x32_bf16(
                    a[i], b[j], acc[i][j], 0, 0, 0);
    }

    float bb[4];
    #pragma unroll
    for (int j = 0; j < 4; j++)
        bb[j] = bias[col0 + wcol + j * 16 + lm];

    #pragma unroll
    for (int i = 0; i < 4; i++) {
        #pragma unroll
        for (int reg = 0; reg < 4; reg++) {
            int r = row0 + wrow + i * 16 + lq * 4 + reg;
            if (r < M) {
                #pragma unroll
                for (int j = 0; j < 4; j++) {
                    int c = col0 + wcol + j * 16 + lm;
                    float v = softplus_f(acc[i][j][reg] + bb[j]);
                    if (out_bf16)
                        ((short*)Cptr)[(size_t)r * Nc + c] = (short)f2bf_rne(v);
                    else
                        ((float*)Cptr)[(size_t)r * Nc + c] = v;
                }
            }
        }
    }
}

// ---------------------------------------------------------------------------
// logits = h2 @ W3 + b3, softmax over K=32 -> att [N,K]
// ---------------------------------------------------------------------------
__global__ __launch_bounds__(256) void logits_softmax(
    const float* __restrict__ h2, const float* __restrict__ W3,
    const float* __restrict__ b3, float* __restrict__ att)
{
    __shared__ float W3s[H2DIM][KCL];
    __shared__ float Hs[256][33];
    __shared__ float b3s[KCL];

    int tid = threadIdx.x;
    int n0 = blockIdx.x * 256;
    int n = n0 + tid;

    for (int idx = tid; idx < H2DIM * KCL; idx += 256)
        ((float*)W3s)[idx] = W3[idx];
    if (tid < KCL) b3s[tid] = b3[tid];

    float acc[KCL] = {};

    for (int t = 0; t < H2DIM / 32; t++) {
        __syncthreads();
        for (int idx = tid; idx < 256 * 32; idx += 256) {
            int r = idx >> 5, c = idx & 31;
            int g = n0 + r;
            Hs[r][c] = (g < NROWS) ? h2[(size_t)g * H2DIM + t * 32 + c] : 0.f;
        }
        __syncthreads();
        #pragma unroll 8
        for (int j = 0; j < 32; j++) {
            float hv = Hs[tid][j];
            #pragma unroll
            for (int k4 = 0; k4 < KCL / 4; k4++) {
                float4 w = *(const float4*)&W3s[t * 32 + j][k4 * 4];
                acc[k4 * 4 + 0] += hv * w.x;
                acc[k4 * 4 + 1] += hv * w.y;
                acc[k4 * 4 + 2] += hv * w.z;
                acc[k4 * 4 + 3] += hv * w.w;
            }
        }
    }

    if (n < NROWS) {
        float m = -INFINITY;
        #pragma unroll
        for (int k = 0; k < KCL; k++) { acc[k] += b3s[k]; m = fmaxf(m, acc[k]); }
        float s = 0.f;
        #pragma unroll
        for (int k = 0; k < KCL; k++) { acc[k] = expf(acc[k] - m); s += acc[k]; }
        float inv = 1.f / s;
        #pragma unroll
        for (int k4 = 0; k4 < KCL / 4; k4++) {
            float4 o;
            o.x = acc[k4 * 4 + 0] * inv;
            o.y = acc[k4 * 4 + 1] * inv;
            o.z = acc[k4 * 4 + 2] * inv;
            o.w = acc[k4 * 4 + 3] * inv;
            *(float4*)&att[(size_t)n * KCL + k4 * 4] = o;
        }
    }
}

// ---------------------------------------------------------------------------
// Partial weighted moments (no atomics; reduced by stats_reduce).
// ---------------------------------------------------------------------------
__global__ __launch_bounds__(256) void stats_partial(
    const float* __restrict__ x, const float* __restrict__ att,
    float* __restrict__ P, float* __restrict__ Patt)
{
    __shared__ float as_[128][32];
    __shared__ float xs[128][32];

    int tid = threadIdx.x;
    int c = blockIdx.x;
    int t = blockIdx.y;
    int k = tid & 31;
    int dg = tid >> 5;

    float s1[4] = {}, s2[4] = {};
    float asum = 0.f;
    int r0 = c * 512;

    for (int sub = 0; sub < 4; sub++) {
        int rr0 = r0 + sub * 128;
        __syncthreads();
        for (int idx = tid; idx < 128 * 32; idx += 256) {
            int r = idx >> 5, cc = idx & 31;
            int g = rr0 + r;
            as_[r][cc] = (g < NROWS) ? att[(size_t)g * KCL + cc] : 0.f;
            xs[r][cc]  = (g < NROWS) ? x[(size_t)g * DDIM + t * 32 + cc] : 0.f;
        }
        __syncthreads();
        for (int r = 0; r < 128; r++) {
            float a = as_[r][k];
            if (dg == 0) asum += a;
            float4 xv = *(const float4*)&xs[r][dg * 4];
            float ax;
            ax = a * xv.x; s1[0] += ax; s2[0] += ax * xv.x;
            ax = a * xv.y; s1[1] += ax; s2[1] += ax * xv.y;
            ax = a * xv.z; s1[2] += ax; s2[2] += ax * xv.z;
            ax = a * xv.w; s1[3] += ax; s2[3] += ax * xv.w;
        }
    }

    size_t base = ((size_t)(t * NCHUNK + c)) * 2048;
    #pragma unroll
    for (int i = 0; i < 4; i++) {
        P[base + k * 32 + dg * 4 + i]        = s1[i];
        P[base + 1024 + k * 32 + dg * 4 + i] = s2[i];
    }
    if (t == 0 && dg == 0) Patt[c * 32 + k] = asum;
}

// ---------------------------------------------------------------------------
// Reduce partials: 128 blocks (16 d-tiles x 8 e-slices), 1 element/thread.
// ---------------------------------------------------------------------------
__global__ __launch_bounds__(256) void stats_reduce(
    const float* __restrict__ P, const float* __restrict__ Patt,
    float* __restrict__ S12, float* __restrict__ att_sum)
{
    int t = blockIdx.x >> 3;
    int s = blockIdx.x & 7;
    int e = s * 256 + threadIdx.x;
    float sum = 0.f;
    for (int c = 0; c < NCHUNK; c++)
        sum += P[((size_t)(t * NCHUNK + c)) * 2048 + e];
    int which = e >> 10;
    int ee = e & 1023;
    int k = ee >> 5, dd = ee & 31;
    S12[(size_t)which * KCL * DDIM + k * DDIM + t * 32 + dd] = sum;

    if (blockIdx.x == 0 && threadIdx.x < KCL) {
        float as = 0.f;
        for (int c = 0; c < NCHUNK; c++) as += Patt[c * 32 + threadIdx.x];
        att_sum[threadIdx.x] = as;
    }
}

// ---------------------------------------------------------------------------
// Finalize stats: vars (to out), bf16 B' = [-0.5/v | m/v] per class, konst.
// ---------------------------------------------------------------------------
__global__ __launch_bounds__(256) void finalize_stats(
    const float* __restrict__ S12, const float* __restrict__ att_sum,
    short* __restrict__ Bp, float* __restrict__ konst,
    float* __restrict__ vars_out)
{
    int k = blockIdx.x;
    int tid = threadIdx.x;
    __shared__ float red[256];

    float inv_as = 1.f / att_sum[k];
    float csum = 0.f, lsum = 0.f;
    for (int d = tid; d < DDIM; d += 256) {
        float mean = S12[k * DDIM + d] * inv_as;
        float ex2  = S12[KCL * DDIM + k * DDIM + d] * inv_as;
        float var  = ex2 - mean * mean;
        vars_out[k * DDIM + d] = var;
        float iv = 1.f / var;
        Bp[(size_t)k * 1024 + d]       = (short)f2bf_rne(-0.5f * iv);
        Bp[(size_t)k * 1024 + 512 + d] = (short)f2bf_rne(mean * iv);
        csum += mean * mean * iv;
        lsum += logf(var);
    }
    red[tid] = csum;
    __syncthreads();
    for (int s = 128; s > 0; s >>= 1) {
        if (tid < s) red[tid] += red[tid + s];
        __syncthreads();
    }
    float ctot = red[0];
    __syncthreads();
    red[tid] = lsum;
    __syncthreads();
    for (int s = 128; s > 0; s >>= 1) {
        if (tid < s) red[tid] += red[tid + s];
        __syncthreads();
    }
    if (tid == 0)
        konst[k] = -0.5f * ctot - 0.5f * red[0] - DDIM * LN2PI_2;
}

// ---------------------------------------------------------------------------
// gmm_log via MFMA: out[n,k] = [x^2|x] @ Bp[k]^T + konst[k].
// ---------------------------------------------------------------------------
#define LDG 40
__global__ __launch_bounds__(256) void gmm_out_mfma(
    const float* __restrict__ x, const short* __restrict__ Bp,
    const float* __restrict__ konst, float* __restrict__ out)
{
    __shared__ short As_sq[256 * LDG];
    __shared__ short As_x[256 * LDG];

    const int tid = threadIdx.x;
    const int lane = tid & 63;
    const int lm = lane & 15;
    const int lq = lane >> 4;
    const int wid = tid >> 6;
    const int row0 = blockIdx.x * 256;

    floatx4 acc[4][2];
    #pragma unroll
    for (int i = 0; i < 4; i++)
        #pragma unroll
        for (int j = 0; j < 2; j++)
            acc[i][j] = (floatx4){0.f, 0.f, 0.f, 0.f};

    for (int dt = 0; dt < 16; dt++) {
        __syncthreads();
        #pragma unroll
        for (int h = 0; h < 8; h++) {
            int u = tid + h * 256;
            int r = u >> 3;
            int seg = (u & 7) << 2;
            int gr = row0 + r;
            float4 v = make_float4(0.f, 0.f, 0.f, 0.f);
            if (gr < NROWS)
                v = *(const float4*)&x[(size_t)gr * DDIM + dt * 32 + seg];
            shortx4 sx, sq;
            sx[0] = (short)f2bf_rne(v.x); sq[0] = (short)f2bf_rne(v.x * v.x);
            sx[1] = (short)f2bf_rne(v.y); sq[1] = (short)f2bf_rne(v.y * v.y);
            sx[2] = (short)f2bf_rne(v.z); sq[2] = (short)f2bf_rne(v.z * v.z);
            sx[3] = (short)f2bf_rne(v.w); sq[3] = (short)f2bf_rne(v.w * v.w);
            *(shortx4*)&As_x[r * LDG + seg]  = sx;
            *(shortx4*)&As_sq[r * LDG + seg] = sq;
        }
        __syncthreads();

        short8 a_sq[4], a_x[4], b_sq[2], b_x[2];
        #pragma unroll
        for (int i = 0; i < 4; i++) {
            int off = (wid * 64 + i * 16 + lm) * LDG + lq * 8;
            a_sq[i] = *(const short8*)&As_sq[off];
            a_x[i]  = *(const short8*)&As_x[off];
        }
        #pragma unroll
        for (int j = 0; j < 2; j++) {
            const size_t bo = (size_t)(j * 16 + lm) * 1024 + dt * 32 + lq * 8;
            b_sq[j] = *(const short8*)&Bp[bo];
            b_x[j]  = *(const short8*)&Bp[bo + 512];
        }
        #pragma unroll
        for (int i = 0; i < 4; i++)
            #pragma unroll
            for (int j = 0; j < 2; j++) {
                acc[i][j] = __builtin_amdgcn_mfma_f32_16x16x32_bf16(
                    a_sq[i], b_sq[j], acc[i][j], 0, 0, 0);
                acc[i][j] = __builtin_amdgcn_mfma_f32_16x16x32_bf16(
                    a_x[i], b_x[j], acc[i][j], 0, 0, 0);
            }
    }

    float kst[2];
    kst[0] = konst[lm];
    kst[1] = konst[16 + lm];

    #pragma unroll
    for (int i = 0; i < 4; i++) {
        #pragma unroll
        for (int reg = 0; reg < 4; reg++) {
            int r = row0 + wid * 64 + i * 16 + lq * 4 + reg;
            if (r < NROWS) {
                out[(size_t)r * KCL + lm]      = acc[i][0][reg] + kst[0];
                out[(size_t)r * KCL + 16 + lm] = acc[i][1][reg] + kst[1];
            }
        }
    }
}

// ---------------------------------------------------------------------------
extern "C" void kernel_launch(void* const* d_in, const int* in_sizes, int n_in,
                              void* d_out, int out_size, void* d_ws, size_t ws_size,
                              hipStream_t stream)
{
    const float* x  = (const float*)d_in[0];
    const float* W1 = (const float*)d_in[1];
    const float* b1 = (const float*)d_in[2];
    const float* W2 = (const float*)d_in[3];
    const float* b2 = (const float*)d_in[4];
    const float* W3 = (const float*)d_in[5];
    const float* b3 = (const float*)d_in[6];
    float* out = (float*)d_out;              // [N*K] gmm_log, then [K*D] vars

    // ws layout:
    short* h1b     = (short*)d_ws;                       // [N][512] bf16
    float* h2      = (float*)(h1b + (size_t)NROWS * H1DIM); // [N][256] fp32
    float* att     = h2 + (size_t)NROWS * H2DIM;
    float* P       = att + (size_t)NROWS * KCL;
    float* Patt    = P + (size_t)16 * NCHUNK * 2048;
    float* S12     = Patt + NCHUNK * KCL;
    float* att_sum = S12 + 2 * KCL * DDIM;
    short* Bp      = (short*)(att_sum + KCL);            // [32][1024] bf16
    float* konst   = (float*)(Bp + KCL * 1024);
    (void)ws_size; (void)in_sizes; (void)n_in; (void)out_size;

    // Overlays (stream-ordered, graph-safe):
    // xb lives in the h2 region: consumed by GEMM1 before GEMM2 writes h2.
    short* xb  = (short*)h2;                 // [N][512] bf16
    // Weight bf16 transposes live at the head of P (dead until stats_partial).
    short* W1T = (short*)P;                  // [512][512]
    short* W2T = W1T + H1DIM * DDIM;         // [256][512]

    cvt_x_bf16<<<dim3(NROWS * DDIM / 2048), 256, 0, stream>>>(x, xb);
    cvt_weightT<<<dim3((DDIM * H1DIM + 255) / 256), 256, 0, stream>>>(
        W1, DDIM, H1DIM, W1T);
    cvt_weightT<<<dim3((H1DIM * H2DIM + 255) / 256), 256, 0, stream>>>(
        W2, H1DIM, H2DIM, W2T);

    int mblocks = (NROWS + 127) / 128;   // 782

    // h1 = softplus(x @ W1 + b1), bf16 out
    gemm_bf16_softplus<<<dim3(H1DIM / 128, mblocks), 256, 0, stream>>>(
        xb, W1T, b1, (void*)h1b, NROWS, H1DIM, DDIM, 1);
    // h2 = softplus(h1 @ W2 + b2), fp32 out
    gemm_bf16_softplus<<<dim3(H2DIM / 128, mblocks), 256, 0, stream>>>(
        h1b, W2T, b2, (void*)h2, NROWS, H2DIM, H1DIM, 0);
    logits_softmax<<<dim3((NROWS + 255) / 256), 256, 0, stream>>>(h2, W3, b3, att);
    stats_partial<<<dim3(NCHUNK, DDIM / 32), 256, 0, stream>>>(x, att, P, Patt);
    stats_reduce<<<dim3(128), 256, 0, stream>>>(P, Patt, S12, att_sum);
    finalize_stats<<<dim3(KCL), 256, 0, stream>>>(
        S12, att_sum, Bp, konst, out + (size_t)NROWS * KCL);
    gmm_out_mfma<<<dim3((NROWS + 255) / 256), 256, 0, stream>>>(x, Bp, konst, out);
}

// Round 6
// 958.934 us; speedup vs baseline: 1.3127x; 1.3127x over previous
//
#include <hip/hip_runtime.h>
#include <hip/hip_bf16.h>
#include <math.h>

// Problem constants
#define NROWS 100000
#define DDIM  512
#define KCL   32
#define H1DIM 512
#define H2DIM 256
#define LN2PI_2 0.9189385332046727f
#define NCHUNK 196   // ceil(100000/512)

typedef __attribute__((ext_vector_type(8))) short short8;
typedef __attribute__((ext_vector_type(4))) short shortx4;
typedef __attribute__((ext_vector_type(4))) float floatx4;

// fast softplus: max(v,0) + log(1+exp(-|v|)); abs err ~1e-6, fine vs bf16 path
__device__ __forceinline__ float softplus_f(float v) {
    return fmaxf(v, 0.f) + __logf(1.f + __expf(-fabsf(v)));
}

__device__ __forceinline__ unsigned short f2bf_rne(float f) {
    unsigned int u = __float_as_uint(f);
    return (unsigned short)((u + 0x7fffu + ((u >> 16) & 1u)) >> 16);
}

// ---------------------------------------------------------------------------
// x (fp32) -> bf16, 8 elements/thread.
// ---------------------------------------------------------------------------
__global__ __launch_bounds__(256) void cvt_x_bf16(
    const float* __restrict__ x, short* __restrict__ xb)
{
    size_t i = ((size_t)blockIdx.x * 256 + threadIdx.x) * 8;
    float4 f0 = *(const float4*)&x[i];
    float4 f1 = *(const float4*)&x[i + 4];
    short8 o;
    o[0] = (short)f2bf_rne(f0.x); o[1] = (short)f2bf_rne(f0.y);
    o[2] = (short)f2bf_rne(f0.z); o[3] = (short)f2bf_rne(f0.w);
    o[4] = (short)f2bf_rne(f1.x); o[5] = (short)f2bf_rne(f1.y);
    o[6] = (short)f2bf_rne(f1.z); o[7] = (short)f2bf_rne(f1.w);
    *(short8*)&xb[i] = o;
}

// ---------------------------------------------------------------------------
// W[k][n] fp32 -> transposed bf16 BT[n][k].
// ---------------------------------------------------------------------------
__global__ __launch_bounds__(256) void cvt_weightT(
    const float* __restrict__ W, int Kd, int Nc, short* __restrict__ BT)
{
    int idx = blockIdx.x * 256 + threadIdx.x;
    if (idx >= Kd * Nc) return;
    int n = idx % Nc, k = idx / Nc;
    BT[(size_t)n * Kd + k] = (short)f2bf_rne(W[idx]);
}

// ---------------------------------------------------------------------------
// C = softplus(A @ B^T + bias). A bf16 [M][Kd], BT bf16 [Nc][Kd].
// 128x128x32 tile, 256 thr (4 waves), 4x4 frags of mfma_f32_16x16x32_bf16.
// Register-prefetch + LDS double-buffer: ONE barrier per iter, global loads
// for iter kt+1 stay in flight across iter kt's compute (latency hiding).
// ---------------------------------------------------------------------------
#define LDP 40   // LDS row stride in shorts (80 B): 2-way-only bank pattern
__global__ __launch_bounds__(256) void gemm_bf16_softplus(
    const short* __restrict__ A, const short* __restrict__ BT,
    const float* __restrict__ bias, void* __restrict__ Cptr,
    int M, int Nc, int Kd, int out_bf16)
{
    __shared__ short As[2][128 * LDP];   // 2 x 10 KB
    __shared__ short Bs[2][128 * LDP];   // 2 x 10 KB

    const int tid = threadIdx.x;
    const int lid = tid & 63;
    const int w = tid >> 6;
    const int lm = lid & 15;
    const int lq = lid >> 4;
    const int wrow = (w & 1) * 64;
    const int wcol = (w >> 1) * 64;

    const int row0 = blockIdx.y * 128;
    const int col0 = blockIdx.x * 128;

    // staging map: thread covers rows {tid>>2, 64+(tid>>2)}, shorts (tid&3)*8
    const int sr = tid >> 2;          // 0..63
    const int sc = (tid & 3) << 3;    // 0,8,16,24

    // clamped global row bases (row clamp is harmless: masked at store)
    int gr0 = row0 + sr;       if (gr0 >= M) gr0 = M - 1;
    int gr1 = row0 + 64 + sr;  if (gr1 >= M) gr1 = M - 1;
    const short* Ar0 = A + (size_t)gr0 * Kd + sc;
    const short* Ar1 = A + (size_t)gr1 * Kd + sc;
    const short* Br0 = BT + (size_t)(col0 + sr) * Kd + sc;
    const short* Br1 = BT + (size_t)(col0 + 64 + sr) * Kd + sc;

    floatx4 acc[4][4];
    #pragma unroll
    for (int i = 0; i < 4; i++)
        #pragma unroll
        for (int j = 0; j < 4; j++)
            acc[i][j] = (floatx4){0.f, 0.f, 0.f, 0.f};

    short8 pa0, pa1, pb0, pb1;
    pa0 = *(const short8*)Ar0;
    pa1 = *(const short8*)Ar1;
    pb0 = *(const short8*)Br0;
    pb1 = *(const short8*)Br1;

    const int nk = Kd >> 5;
    for (int kt = 0; kt < nk; kt++) {
        const int buf = kt & 1;
        // store prefetched tile
        *(short8*)&As[buf][sr * LDP + sc]        = pa0;
        *(short8*)&As[buf][(64 + sr) * LDP + sc] = pa1;
        *(short8*)&Bs[buf][sr * LDP + sc]        = pb0;
        *(short8*)&Bs[buf][(64 + sr) * LDP + sc] = pb1;
        // issue next tile's loads (in flight across compute below)
        if (kt + 1 < nk) {
            int ko = (kt + 1) << 5;
            pa0 = *(const short8*)(Ar0 + ko);
            pa1 = *(const short8*)(Ar1 + ko);
            pb0 = *(const short8*)(Br0 + ko);
            pb1 = *(const short8*)(Br1 + ko);
        }
        __syncthreads();

        short8 a[4], b[4];
        #pragma unroll
        for (int i = 0; i < 4; i++)
            a[i] = *(const short8*)&As[buf][(wrow + i * 16 + lm) * LDP + lq * 8];
        #pragma unroll
        for (int j = 0; j < 4; j++)
            b[j] = *(const short8*)&Bs[buf][(wcol + j * 16 + lm) * LDP + lq * 8];
        #pragma unroll
        for (int i = 0; i < 4; i++)
            #pragma unroll
            for (int j = 0; j < 4; j++)
                acc[i][j] = __builtin_amdgcn_mfma_f32_16x16x32_bf16(
                    a[i], b[j], acc[i][j], 0, 0, 0);
    }

    float bb[4];
    #pragma unroll
    for (int j = 0; j < 4; j++)
        bb[j] = bias[col0 + wcol + j * 16 + lm];

    #pragma unroll
    for (int i = 0; i < 4; i++) {
        #pragma unroll
        for (int reg = 0; reg < 4; reg++) {
            int r = row0 + wrow + i * 16 + lq * 4 + reg;
            if (r < M) {
                #pragma unroll
                for (int j = 0; j < 4; j++) {
                    int c = col0 + wcol + j * 16 + lm;
                    float v = softplus_f(acc[i][j][reg] + bb[j]);
                    if (out_bf16)
                        ((short*)Cptr)[(size_t)r * Nc + c] = (short)f2bf_rne(v);
                    else
                        ((float*)Cptr)[(size_t)r * Nc + c] = v;
                }
            }
        }
    }
}

// ---------------------------------------------------------------------------
// logits = h2 @ W3 + b3, softmax over K=32 -> att [N,K]
// ---------------------------------------------------------------------------
__global__ __launch_bounds__(256) void logits_softmax(
    const float* __restrict__ h2, const float* __restrict__ W3,
    const float* __restrict__ b3, float* __restrict__ att)
{
    __shared__ float W3s[H2DIM][KCL];
    __shared__ float Hs[256][33];
    __shared__ float b3s[KCL];

    int tid = threadIdx.x;
    int n0 = blockIdx.x * 256;
    int n = n0 + tid;

    for (int idx = tid; idx < H2DIM * KCL; idx += 256)
        ((float*)W3s)[idx] = W3[idx];
    if (tid < KCL) b3s[tid] = b3[tid];

    float acc[KCL] = {};

    for (int t = 0; t < H2DIM / 32; t++) {
        __syncthreads();
        for (int idx = tid; idx < 256 * 32; idx += 256) {
            int r = idx >> 5, c = idx & 31;
            int g = n0 + r;
            Hs[r][c] = (g < NROWS) ? h2[(size_t)g * H2DIM + t * 32 + c] : 0.f;
        }
        __syncthreads();
        #pragma unroll 8
        for (int j = 0; j < 32; j++) {
            float hv = Hs[tid][j];
            #pragma unroll
            for (int k4 = 0; k4 < KCL / 4; k4++) {
                float4 w = *(const float4*)&W3s[t * 32 + j][k4 * 4];
                acc[k4 * 4 + 0] += hv * w.x;
                acc[k4 * 4 + 1] += hv * w.y;
                acc[k4 * 4 + 2] += hv * w.z;
                acc[k4 * 4 + 3] += hv * w.w;
            }
        }
    }

    if (n < NROWS) {
        float m = -INFINITY;
        #pragma unroll
        for (int k = 0; k < KCL; k++) { acc[k] += b3s[k]; m = fmaxf(m, acc[k]); }
        float s = 0.f;
        #pragma unroll
        for (int k = 0; k < KCL; k++) { acc[k] = __expf(acc[k] - m); s += acc[k]; }
        float inv = 1.f / s;
        #pragma unroll
        for (int k4 = 0; k4 < KCL / 4; k4++) {
            float4 o;
            o.x = acc[k4 * 4 + 0] * inv;
            o.y = acc[k4 * 4 + 1] * inv;
            o.z = acc[k4 * 4 + 2] * inv;
            o.w = acc[k4 * 4 + 3] * inv;
            *(float4*)&att[(size_t)n * KCL + k4 * 4] = o;
        }
    }
}

// ---------------------------------------------------------------------------
// Partial weighted moments (no atomics; reduced by stats_reduce).
// ---------------------------------------------------------------------------
__global__ __launch_bounds__(256) void stats_partial(
    const float* __restrict__ x, const float* __restrict__ att,
    float* __restrict__ P, float* __restrict__ Patt)
{
    __shared__ float as_[128][32];
    __shared__ float xs[128][32];

    int tid = threadIdx.x;
    int c = blockIdx.x;
    int t = blockIdx.y;
    int k = tid & 31;
    int dg = tid >> 5;

    float s1[4] = {}, s2[4] = {};
    float asum = 0.f;
    int r0 = c * 512;

    for (int sub = 0; sub < 4; sub++) {
        int rr0 = r0 + sub * 128;
        __syncthreads();
        for (int idx = tid; idx < 128 * 32; idx += 256) {
            int r = idx >> 5, cc = idx & 31;
            int g = rr0 + r;
            as_[r][cc] = (g < NROWS) ? att[(size_t)g * KCL + cc] : 0.f;
            xs[r][cc]  = (g < NROWS) ? x[(size_t)g * DDIM + t * 32 + cc] : 0.f;
        }
        __syncthreads();
        for (int r = 0; r < 128; r++) {
            float a = as_[r][k];
            if (dg == 0) asum += a;
            float4 xv = *(const float4*)&xs[r][dg * 4];
            float ax;
            ax = a * xv.x; s1[0] += ax; s2[0] += ax * xv.x;
            ax = a * xv.y; s1[1] += ax; s2[1] += ax * xv.y;
            ax = a * xv.z; s1[2] += ax; s2[2] += ax * xv.z;
            ax = a * xv.w; s1[3] += ax; s2[3] += ax * xv.w;
        }
    }

    size_t base = ((size_t)(t * NCHUNK + c)) * 2048;
    #pragma unroll
    for (int i = 0; i < 4; i++) {
        P[base + k * 32 + dg * 4 + i]        = s1[i];
        P[base + 1024 + k * 32 + dg * 4 + i] = s2[i];
    }
    if (t == 0 && dg == 0) Patt[c * 32 + k] = asum;
}

// ---------------------------------------------------------------------------
// Reduce partials: 128 blocks (16 d-tiles x 8 e-slices), 1 element/thread.
// ---------------------------------------------------------------------------
__global__ __launch_bounds__(256) void stats_reduce(
    const float* __restrict__ P, const float* __restrict__ Patt,
    float* __restrict__ S12, float* __restrict__ att_sum)
{
    int t = blockIdx.x >> 3;
    int s = blockIdx.x & 7;
    int e = s * 256 + threadIdx.x;
    float sum = 0.f;
    for (int c = 0; c < NCHUNK; c++)
        sum += P[((size_t)(t * NCHUNK + c)) * 2048 + e];
    int which = e >> 10;
    int ee = e & 1023;
    int k = ee >> 5, dd = ee & 31;
    S12[(size_t)which * KCL * DDIM + k * DDIM + t * 32 + dd] = sum;

    if (blockIdx.x == 0 && threadIdx.x < KCL) {
        float as = 0.f;
        for (int c = 0; c < NCHUNK; c++) as += Patt[c * 32 + threadIdx.x];
        att_sum[threadIdx.x] = as;
    }
}

// ---------------------------------------------------------------------------
// Finalize stats: vars (to out), bf16 B' = [-0.5/v | m/v] per class, konst.
// ---------------------------------------------------------------------------
__global__ __launch_bounds__(256) void finalize_stats(
    const float* __restrict__ S12, const float* __restrict__ att_sum,
    short* __restrict__ Bp, float* __restrict__ konst,
    float* __restrict__ vars_out)
{
    int k = blockIdx.x;
    int tid = threadIdx.x;
    __shared__ float red[256];

    float inv_as = 1.f / att_sum[k];
    float csum = 0.f, lsum = 0.f;
    for (int d = tid; d < DDIM; d += 256) {
        float mean = S12[k * DDIM + d] * inv_as;
        float ex2  = S12[KCL * DDIM + k * DDIM + d] * inv_as;
        float var  = ex2 - mean * mean;
        vars_out[k * DDIM + d] = var;
        float iv = 1.f / var;
        Bp[(size_t)k * 1024 + d]       = (short)f2bf_rne(-0.5f * iv);
        Bp[(size_t)k * 1024 + 512 + d] = (short)f2bf_rne(mean * iv);
        csum += mean * mean * iv;
        lsum += logf(var);
    }
    red[tid] = csum;
    __syncthreads();
    for (int s = 128; s > 0; s >>= 1) {
        if (tid < s) red[tid] += red[tid + s];
        __syncthreads();
    }
    float ctot = red[0];
    __syncthreads();
    red[tid] = lsum;
    __syncthreads();
    for (int s = 128; s > 0; s >>= 1) {
        if (tid < s) red[tid] += red[tid + s];
        __syncthreads();
    }
    if (tid == 0)
        konst[k] = -0.5f * ctot - 0.5f * red[0] - DDIM * LN2PI_2;
}

// ---------------------------------------------------------------------------
// gmm_log via MFMA: out[n,k] = [x^2|x] @ Bp[k]^T + konst[k].
// ---------------------------------------------------------------------------
#define LDG 40
__global__ __launch_bounds__(256) void gmm_out_mfma(
    const float* __restrict__ x, const short* __restrict__ Bp,
    const float* __restrict__ konst, float* __restrict__ out)
{
    __shared__ short As_sq[256 * LDG];
    __shared__ short As_x[256 * LDG];

    const int tid = threadIdx.x;
    const int lane = tid & 63;
    const int lm = lane & 15;
    const int lq = lane >> 4;
    const int wid = tid >> 6;
    const int row0 = blockIdx.x * 256;

    floatx4 acc[4][2];
    #pragma unroll
    for (int i = 0; i < 4; i++)
        #pragma unroll
        for (int j = 0; j < 2; j++)
            acc[i][j] = (floatx4){0.f, 0.f, 0.f, 0.f};

    for (int dt = 0; dt < 16; dt++) {
        __syncthreads();
        #pragma unroll
        for (int h = 0; h < 8; h++) {
            int u = tid + h * 256;
            int r = u >> 3;
            int seg = (u & 7) << 2;
            int gr = row0 + r;
            float4 v = make_float4(0.f, 0.f, 0.f, 0.f);
            if (gr < NROWS)
                v = *(const float4*)&x[(size_t)gr * DDIM + dt * 32 + seg];
            shortx4 sx, sq;
            sx[0] = (short)f2bf_rne(v.x); sq[0] = (short)f2bf_rne(v.x * v.x);
            sx[1] = (short)f2bf_rne(v.y); sq[1] = (short)f2bf_rne(v.y * v.y);
            sx[2] = (short)f2bf_rne(v.z); sq[2] = (short)f2bf_rne(v.z * v.z);
            sx[3] = (short)f2bf_rne(v.w); sq[3] = (short)f2bf_rne(v.w * v.w);
            *(shortx4*)&As_x[r * LDG + seg]  = sx;
            *(shortx4*)&As_sq[r * LDG + seg] = sq;
        }
        __syncthreads();

        short8 a_sq[4], a_x[4], b_sq[2], b_x[2];
        #pragma unroll
        for (int i = 0; i < 4; i++) {
            int off = (wid * 64 + i * 16 + lm) * LDG + lq * 8;
            a_sq[i] = *(const short8*)&As_sq[off];
            a_x[i]  = *(const short8*)&As_x[off];
        }
        #pragma unroll
        for (int j = 0; j < 2; j++) {
            const size_t bo = (size_t)(j * 16 + lm) * 1024 + dt * 32 + lq * 8;
            b_sq[j] = *(const short8*)&Bp[bo];
            b_x[j]  = *(const short8*)&Bp[bo + 512];
        }
        #pragma unroll
        for (int i = 0; i < 4; i++)
            #pragma unroll
            for (int j = 0; j < 2; j++) {
                acc[i][j] = __builtin_amdgcn_mfma_f32_16x16x32_bf16(
                    a_sq[i], b_sq[j], acc[i][j], 0, 0, 0);
                acc[i][j] = __builtin_amdgcn_mfma_f32_16x16x32_bf16(
                    a_x[i], b_x[j], acc[i][j], 0, 0, 0);
            }
    }

    float kst[2];
    kst[0] = konst[lm];
    kst[1] = konst[16 + lm];

    #pragma unroll
    for (int i = 0; i < 4; i++) {
        #pragma unroll
        for (int reg = 0; reg < 4; reg++) {
            int r = row0 + wid * 64 + i * 16 + lq * 4 + reg;
            if (r < NROWS) {
                out[(size_t)r * KCL + lm]      = acc[i][0][reg] + kst[0];
                out[(size_t)r * KCL + 16 + lm] = acc[i][1][reg] + kst[1];
            }
        }
    }
}

// ---------------------------------------------------------------------------
extern "C" void kernel_launch(void* const* d_in, const int* in_sizes, int n_in,
                              void* d_out, int out_size, void* d_ws, size_t ws_size,
                              hipStream_t stream)
{
    const float* x  = (const float*)d_in[0];
    const float* W1 = (const float*)d_in[1];
    const float* b1 = (const float*)d_in[2];
    const float* W2 = (const float*)d_in[3];
    const float* b2 = (const float*)d_in[4];
    const float* W3 = (const float*)d_in[5];
    const float* b3 = (const float*)d_in[6];
    float* out = (float*)d_out;              // [N*K] gmm_log, then [K*D] vars

    // ws layout:
    short* h1b     = (short*)d_ws;                       // [N][512] bf16
    float* h2      = (float*)(h1b + (size_t)NROWS * H1DIM); // [N][256] fp32
    float* att     = h2 + (size_t)NROWS * H2DIM;
    float* P       = att + (size_t)NROWS * KCL;
    float* Patt    = P + (size_t)16 * NCHUNK * 2048;
    float* S12     = Patt + NCHUNK * KCL;
    float* att_sum = S12 + 2 * KCL * DDIM;
    short* Bp      = (short*)(att_sum + KCL);            // [32][1024] bf16
    float* konst   = (float*)(Bp + KCL * 1024);
    (void)ws_size; (void)in_sizes; (void)n_in; (void)out_size;

    // Overlays (stream-ordered, graph-safe):
    // xb lives in the h2 region: consumed by GEMM1 before GEMM2 writes h2.
    short* xb  = (short*)h2;                 // [N][512] bf16
    // Weight bf16 transposes live at the head of P (dead until stats_partial).
    short* W1T = (short*)P;                  // [512][512]
    short* W2T = W1T + H1DIM * DDIM;         // [256][512]

    cvt_x_bf16<<<dim3(NROWS * DDIM / 2048), 256, 0, stream>>>(x, xb);
    cvt_weightT<<<dim3((DDIM * H1DIM + 255) / 256), 256, 0, stream>>>(
        W1, DDIM, H1DIM, W1T);
    cvt_weightT<<<dim3((H1DIM * H2DIM + 255) / 256), 256, 0, stream>>>(
        W2, H1DIM, H2DIM, W2T);

    int mblocks = (NROWS + 127) / 128;   // 782

    // h1 = softplus(x @ W1 + b1), bf16 out
    gemm_bf16_softplus<<<dim3(H1DIM / 128, mblocks), 256, 0, stream>>>(
        xb, W1T, b1, (void*)h1b, NROWS, H1DIM, DDIM, 1);
    // h2 = softplus(h1 @ W2 + b2), fp32 out
    gemm_bf16_softplus<<<dim3(H2DIM / 128, mblocks), 256, 0, stream>>>(
        h1b, W2T, b2, (void*)h2, NROWS, H2DIM, H1DIM, 0);
    logits_softmax<<<dim3((NROWS + 255) / 256), 256, 0, stream>>>(h2, W3, b3, att);
    stats_partial<<<dim3(NCHUNK, DDIM / 32), 256, 0, stream>>>(x, att, P, Patt);
    stats_reduce<<<dim3(128), 256, 0, stream>>>(P, Patt, S12, att_sum);
    finalize_stats<<<dim3(KCL), 256, 0, stream>>>(
        S12, att_sum, Bp, konst, out + (size_t)NROWS * KCL);
    gmm_out_mfma<<<dim3((NROWS + 255) / 256), 256, 0, stream>>>(x, Bp, konst, out);
}